// Round 12
// baseline (465.709 us; speedup 1.0000x reference)
//
#include <hip/hip_runtime.h>
#include <hip/hip_bf16.h>

#define CDIM 128
#define SCAN_CHUNK 2048   // elements per scan block (256 thr x 8)

typedef __attribute__((ext_vector_type(4))) float f32x4;
typedef __attribute__((ext_vector_type(8))) short bf16x8;
typedef __attribute__((ext_vector_type(4))) short bf16x4;

// RNE f32->bf16
__device__ __forceinline__ short f2bf(float f) {
    unsigned u = __float_as_uint(f);
    u += 0x7FFFu + ((u >> 16) & 1u);
    return (short)(u >> 16);
}
__device__ __forceinline__ unsigned pack2bf(float a, float b) {
    return (unsigned)(unsigned short)f2bf(a) | ((unsigned)(unsigned short)f2bf(b) << 16);
}

// ---------------- CSR build ----------------

__global__ __launch_bounds__(256) void zero_ints(int* __restrict__ p, int n) {
    int i = blockIdx.x * 256 + threadIdx.x;
    for (; i < n; i += gridDim.x * 256) p[i] = 0;
}

// histogram + per-edge rank within destination (atomicAdd return value)
__global__ __launch_bounds__(256) void hist_rank(
    const int* __restrict__ c1, int nnz1, const int* __restrict__ c2, int nnz2,
    int n1, int* __restrict__ counts, int* __restrict__ rank)
{
    const int gtid = blockIdx.x * 256 + threadIdx.x;
    const int gstride = gridDim.x * 256;
    for (int e = gtid; e < nnz1; e += gstride)
        rank[e] = atomicAdd(&counts[c1[e]], 1);
    for (int e = gtid; e < nnz2; e += gstride)
        rank[nnz1 + e] = atomicAdd(&counts[n1 + c2[e]], 1);
}

// per-chunk exclusive scan; chunk total -> bsums[chunk]
__global__ __launch_bounds__(256) void scan_chunks(const int* __restrict__ in, int* __restrict__ out,
                                                   int* __restrict__ bsums, int n) {
    __shared__ int wtot[4];
    const int t = threadIdx.x;
    const int base = blockIdx.x * SCAN_CHUNK + t * 8;
    int v[8]; int s = 0;
#pragma unroll
    for (int j = 0; j < 8; ++j) {
        int c = (base + j < n) ? in[base + j] : 0;
        v[j] = s; s += c;
    }
    const int lane = t & 63, w = t >> 6;
    int inc = s;
#pragma unroll
    for (int d = 1; d < 64; d <<= 1) {
        int o = __shfl_up(inc, d);
        if (lane >= d) inc += o;
    }
    if (lane == 63) wtot[w] = inc;
    __syncthreads();
    int off = inc - s;
    for (int i = 0; i < w; ++i) off += wtot[i];
#pragma unroll
    for (int j = 0; j < 8; ++j)
        if (base + j < n) out[base + j] = v[j] + off;
    if (t == 255) bsums[blockIdx.x] = off + s;
}

// block b: add sum(bsums[0..b)) to its chunk of row_ptr; set row_ptr[N]
__global__ __launch_bounds__(256) void scan_finalize(int* __restrict__ row_ptr,
                                                     const int* __restrict__ bsums,
                                                     int n, int nnzT) {
    __shared__ int wsum[4];
    const int t = threadIdx.x, lane = t & 63, w = t >> 6;
    int s = 0;
    for (int i = t; i < (int)blockIdx.x; i += 256) s += bsums[i];
#pragma unroll
    for (int d = 1; d < 64; d <<= 1) s += __shfl_xor(s, d);
    if (lane == 0) wsum[w] = s;
    __syncthreads();
    const int off = wsum[0] + wsum[1] + wsum[2] + wsum[3];
    const int base = blockIdx.x * SCAN_CHUNK + t * 8;
#pragma unroll
    for (int j = 0; j < 8; ++j) {
        const int i = base + j;
        if (i < n) row_ptr[i] += off;
    }
    if (blockIdx.x == 0 && t == 0) row_ptr[n] = nnzT;
}

// atomic-free scatter: pos = row_ptr[dest] + rank[e]
__global__ __launch_bounds__(256) void scatter_both(
    const int* __restrict__ r1, const int* __restrict__ c1, const float* __restrict__ v1, int nnz1,
    const int* __restrict__ r2, const int* __restrict__ c2, const float* __restrict__ v2, int nnz2,
    int n1, const int* __restrict__ row_ptr, const int* __restrict__ rank,
    unsigned long long* __restrict__ csr)
{
    const int gtid = blockIdx.x * 256 + threadIdx.x;
    const int gstride = gridDim.x * 256;
    for (int e = gtid; e < nnz1; e += gstride) {
        int p = row_ptr[c1[e]] + rank[e];
        csr[p] = ((unsigned long long)__float_as_uint(__builtin_nontemporal_load(&v1[e])) << 32)
                 | (unsigned)__builtin_nontemporal_load(&r1[e]);
    }
    for (int e = gtid; e < nnz2; e += gstride) {
        int p = row_ptr[n1 + c2[e]] + rank[nnz1 + e];
        csr[p] = ((unsigned long long)__float_as_uint(__builtin_nontemporal_load(&v2[e])) << 32)
                 | (unsigned)__builtin_nontemporal_load(&r2[e]);
    }
}

// ---------------- dense GEMM: h = bf16(x @ W), both inputs in one launch ----------------
// Epilogue: shfl_xor(16) pair-exchange -> each lane stores 16B; per a-iteration
// the wave's 64 lanes cover a full 64B span of each of 16 rows (full sectors).
// Span ownership: lane l4 stores cols [(2a+sel)*16 + qpos*8, +8); its own quad
// sits at position sel within the span, partner's (l4^1) at position sel^1.
__global__ __launch_bounds__(256) void gemm_all(
    const float* __restrict__ x0, const float* __restrict__ W1, short* __restrict__ h0, int t0,
    const float* __restrict__ x1, const float* __restrict__ W2, short* __restrict__ h1, int t1,
    int g0)
{
    const float* __restrict__ x; const float* __restrict__ W; short* __restrict__ h;
    int ntiles, bidx, nblk;
    if ((int)blockIdx.x < g0) { x = x0; W = W1; h = h0; ntiles = t0; bidx = blockIdx.x;       nblk = g0; }
    else                      { x = x1; W = W2; h = h1; ntiles = t1; bidx = blockIdx.x - g0; nblk = gridDim.x - g0; }

    __shared__ short Bfrag[4][8][64][8];   // [kk][nb][lane][j] = 32 KB, lane-linear 16B slots
    for (int slot = threadIdx.x; slot < 2048; slot += 256) {
        const int lane = slot & 63, nb = (slot >> 6) & 7, kk = slot >> 9;
        const int n  = nb * 16 + (lane & 15);
        const int k0 = kk * 32 + (lane >> 4) * 8;
        union { bf16x8 v; short s[8]; } f;
#pragma unroll
        for (int j = 0; j < 8; ++j) f.s[j] = f2bf(W[(k0 + j) * CDIM + n]);
        *(bf16x8*)&Bfrag[kk][nb][lane][0] = f.v;
    }
    __syncthreads();

    const int lane = threadIdx.x & 63;
    const int wid  = threadIdx.x >> 6;
    const int l15  = lane & 15;
    const int l4   = lane >> 4;

    for (int tile = bidx * 4 + wid; tile < ntiles; tile += nblk * 4) {
        const int rbase = tile << 4;
        const int row = rbase + l15;
        const float* __restrict__ xr = x + (long)row * CDIM + (l4 << 3);

        union { bf16x8 v; short s[8]; } X[4];
#pragma unroll
        for (int kk = 0; kk < 4; ++kk) {
            f32x4 a0 = __builtin_nontemporal_load((const f32x4*)(xr + kk * 32));
            f32x4 a1 = __builtin_nontemporal_load((const f32x4*)(xr + kk * 32 + 4));
#pragma unroll
            for (int j = 0; j < 4; ++j) { X[kk].s[j] = f2bf(a0[j]); X[kk].s[4 + j] = f2bf(a1[j]); }
        }

        f32x4 c[8];
#pragma unroll
        for (int nb = 0; nb < 8; ++nb) c[nb] = (f32x4){0.f, 0.f, 0.f, 0.f};
#pragma unroll
        for (int kk = 0; kk < 4; ++kk)
#pragma unroll
            for (int nb = 0; nb < 8; ++nb)
                c[nb] = __builtin_amdgcn_mfma_f32_16x16x32_bf16(
                            *(const bf16x8*)&Bfrag[kk][nb][lane][0], X[kk].v, c[nb], 0, 0, 0);

        // c[nb][ri] = h[row][nb*16 + l4*4 + ri]
        short* __restrict__ hrow = h + (long)row * CDIM;
        const int sel = l4 & 1;           // which nb of the pair this lane stores
        const int qpos = l4 >> 1;         // which 8-col half of that nb
#pragma unroll
        for (int a = 0; a < 4; ++a) {
            const f32x4 mine = c[2 * a + sel];
            const f32x4 send = c[2 * a + (sel ^ 1)];
            unsigned own0 = pack2bf(mine[0], mine[1]);
            unsigned own1 = pack2bf(mine[2], mine[3]);
            unsigned snd0 = pack2bf(send[0], send[1]);
            unsigned snd1 = pack2bf(send[2], send[3]);
            unsigned rcv0 = __shfl_xor((int)snd0, 16);
            unsigned rcv1 = __shfl_xor((int)snd1, 16);
            union { unsigned u[4]; bf16x8 v; } st;
            if (sel == 0) {                // own quad is first within the span
                st.u[0] = own0; st.u[1] = own1; st.u[2] = rcv0; st.u[3] = rcv1;
            } else {                       // own quad is second within the span
                st.u[0] = rcv0; st.u[1] = rcv1; st.u[2] = own0; st.u[3] = own1;
            }
            *(bf16x8*)(hrow + (2 * a + sel) * 16 + qpos * 8) = st.v;
        }
    }
}

// ---------------- gather-aggregate-sigmoid ----------------
// 16 lanes per dest row. Lane t16 fetches csr[beg+t16] (one load covers <=16
// edges). Batch-of-6 gathers issued back-to-back before any FMA.
__global__ __launch_bounds__(256, 8) void agg_all(
    const short* __restrict__ h0, const short* __restrict__ h1,
    const int* __restrict__ row_ptr, const unsigned long long* __restrict__ csr,
    float* __restrict__ out, int n1, int nnzT)
{
    const int lane = threadIdx.x & 63;
    const int wid  = threadIdx.x >> 6;
    const int g    = lane >> 4;
    const int t16  = lane & 15;
    const int r = blockIdx.x * 16 + wid * 4 + g;
    const short* __restrict__ h = (r < n1) ? h0 : h1;   // n1 % 16 == 0 -> block-uniform
    const int beg = row_ptr[r];
    const int end = row_ptr[r + 1];
    const int deg = end - beg;

    int fi = beg + t16; if (fi > nnzT - 1) fi = nnzT - 1;
    const unsigned long long my = __builtin_nontemporal_load(&csr[fi]);

    const int m = deg < 16 ? deg : 16;
    const int gbase = g << 4;
    float acc[8] = {0.f, 0.f, 0.f, 0.f, 0.f, 0.f, 0.f, 0.f};

    bf16x8 hv[6]; float vv[6];
#pragma unroll
    for (int j0 = 0; j0 < 18; j0 += 6) {
        if (j0 > 0 && !__any(m > j0)) break;
#pragma unroll
        for (int j = 0; j < 6; ++j) {
            const int e = j0 + j;
            if (e < m) {
                unsigned long long pv = __shfl(my, gbase + e);
                vv[j] = __uint_as_float((unsigned)(pv >> 32));
                hv[j] = *(const bf16x8*)(h + (long)(unsigned)(pv & 0xffffffffu) * CDIM + (t16 << 3));
            }
        }
#pragma unroll
        for (int j = 0; j < 6; ++j) {
            const int e = j0 + j;
            if (e < m) {
                union { bf16x8 v; unsigned u[4]; } H; H.v = hv[j];
#pragma unroll
                for (int d = 0; d < 4; ++d) {
                    acc[2 * d]     += vv[j] * __uint_as_float(H.u[d] << 16);
                    acc[2 * d + 1] += vv[j] * __uint_as_float(H.u[d] & 0xffff0000u);
                }
            }
        }
    }
    // serial tail for deg > 16 (statistically ~never; correctness only)
    for (int i = beg + 16; i < end; ++i) {
        const unsigned long long pv = csr[i];
        const float val = __uint_as_float((unsigned)(pv >> 32));
        union { bf16x8 v; unsigned u[4]; } H;
        H.v = *(const bf16x8*)(h + (long)(unsigned)(pv & 0xffffffffu) * CDIM + (t16 << 3));
#pragma unroll
        for (int d = 0; d < 4; ++d) {
            acc[2 * d]     += val * __uint_as_float(H.u[d] << 16);
            acc[2 * d + 1] += val * __uint_as_float(H.u[d] & 0xffff0000u);
        }
    }

    f32x4 o0, o1;
#pragma unroll
    for (int j = 0; j < 4; ++j) {
        o0[j] = 1.0f / (1.0f + __expf(-acc[j]));
        o1[j] = 1.0f / (1.0f + __expf(-acc[4 + j]));
    }
    float* __restrict__ orow = out + (long)r * CDIM + (t16 << 3);
    __builtin_nontemporal_store(o0, (f32x4*)orow);
    __builtin_nontemporal_store(o1, (f32x4*)(orow + 4));
}

// ---------------- launch ----------------

extern "C" void kernel_launch(void* const* d_in, const int* in_sizes, int n_in,
                              void* d_out, int out_size, void* d_ws, size_t ws_size,
                              hipStream_t stream) {
    const float* x0 = (const float*)d_in[0];
    const float* x1 = (const float*)d_in[1];
    const float* W1 = (const float*)d_in[3];
    const float* W2 = (const float*)d_in[4];
    const int*   b1r = (const int*)d_in[5];
    const int*   b1c = (const int*)d_in[6];
    const float* b1v = (const float*)d_in[7];
    const int*   b2r = (const int*)d_in[8];
    const int*   b2c = (const int*)d_in[9];
    const float* b2v = (const float*)d_in[10];
    const int nnz1 = in_sizes[5];
    const int nnz2 = in_sizes[8];
    const int n0 = in_sizes[0] / CDIM;   // 100000
    const int n1 = in_sizes[1] / CDIM;   // 400000 (x1 rows = out1 rows)
    const int n2 = in_sizes[2] / CDIM;   // 300000
    const int N  = n1 + n2;              // combined dest space
    const int nnzT = nnz1 + nnz2;

    // workspace carve-up (ints unless noted)
    int* counts  = (int*)d_ws;                 // N
    int* row_ptr = counts + N;                 // N+1
    int* rank    = row_ptr + N + 1;            // nnzT
    int* bsums   = rank + nnzT;                // 512
    size_t iofs = (size_t)2 * N + 1 + nnzT + 512;
    iofs = (iofs + 1) & ~(size_t)1;            // 8B align
    unsigned long long* csr = (unsigned long long*)((int*)d_ws + iofs);  // nnzT (8B each)
    short* h0 = (short*)(csr + nnzT);          // n0*128 bf16
    short* h1 = h0 + (size_t)n0 * CDIM;        // n1*128 bf16

    float* out = (float*)d_out;                // rows [0, N) x 128

    const int nchunks = (N + SCAN_CHUNK - 1) / SCAN_CHUNK;  // 342 <= 512

    zero_ints<<<1024, 256, 0, stream>>>(counts, N);
    hist_rank<<<2048, 256, 0, stream>>>(b1c, nnz1, b2c, nnz2, n1, counts, rank);
    scan_chunks<<<nchunks, 256, 0, stream>>>(counts, row_ptr, bsums, N);
    scan_finalize<<<nchunks, 256, 0, stream>>>(row_ptr, bsums, N, nnzT);
    scatter_both<<<2048, 256, 0, stream>>>(b1r, b1c, b1v, nnz1, b2r, b2c, b2v, nnz2,
                                           n1, row_ptr, rank, csr);

    const int t0 = n0 >> 4, t1 = n1 >> 4;
    gemm_all<<<2048, 256, 0, stream>>>(x0, W1, h0, t0, x1, W2, h1, t1, 416);

    agg_all<<<N >> 4, 256, 0, stream>>>(h0, h1, row_ptr, csr, out, n1, nnzT);
}

// Round 13
// 400.551 us; speedup vs baseline: 1.1627x; 1.1627x over previous
//
#include <hip/hip_runtime.h>
#include <hip/hip_bf16.h>

#define CDIM 128
#define SCAN_CHUNK 2048   // elements per scan block (256 thr x 8)

typedef __attribute__((ext_vector_type(4))) float f32x4;
typedef __attribute__((ext_vector_type(8))) short bf16x8;
typedef __attribute__((ext_vector_type(4))) short bf16x4;

// RNE f32->bf16
__device__ __forceinline__ short f2bf(float f) {
    unsigned u = __float_as_uint(f);
    u += 0x7FFFu + ((u >> 16) & 1u);
    return (short)(u >> 16);
}

// ---------------- CSR build ----------------

__global__ __launch_bounds__(256) void zero_ints(int* __restrict__ p, int n) {
    int i = blockIdx.x * 256 + threadIdx.x;
    for (; i < n; i += gridDim.x * 256) p[i] = 0;
}

// histogram + per-edge rank within destination (atomicAdd return value)
__global__ __launch_bounds__(256) void hist_rank(
    const int* __restrict__ c1, int nnz1, const int* __restrict__ c2, int nnz2,
    int n1, int* __restrict__ counts, int* __restrict__ rank)
{
    const int gtid = blockIdx.x * 256 + threadIdx.x;
    const int gstride = gridDim.x * 256;
    for (int e = gtid; e < nnz1; e += gstride)
        rank[e] = atomicAdd(&counts[c1[e]], 1);
    for (int e = gtid; e < nnz2; e += gstride)
        rank[nnz1 + e] = atomicAdd(&counts[n1 + c2[e]], 1);
}

// per-chunk exclusive scan; chunk total -> bsums[chunk]
__global__ __launch_bounds__(256) void scan_chunks(const int* __restrict__ in, int* __restrict__ out,
                                                   int* __restrict__ bsums, int n) {
    __shared__ int wtot[4];
    const int t = threadIdx.x;
    const int base = blockIdx.x * SCAN_CHUNK + t * 8;
    int v[8]; int s = 0;
#pragma unroll
    for (int j = 0; j < 8; ++j) {
        int c = (base + j < n) ? in[base + j] : 0;
        v[j] = s; s += c;
    }
    const int lane = t & 63, w = t >> 6;
    int inc = s;
#pragma unroll
    for (int d = 1; d < 64; d <<= 1) {
        int o = __shfl_up(inc, d);
        if (lane >= d) inc += o;
    }
    if (lane == 63) wtot[w] = inc;
    __syncthreads();
    int off = inc - s;
    for (int i = 0; i < w; ++i) off += wtot[i];
#pragma unroll
    for (int j = 0; j < 8; ++j)
        if (base + j < n) out[base + j] = v[j] + off;
    if (t == 255) bsums[blockIdx.x] = off + s;
}

// block b: add sum(bsums[0..b)) to its chunk of row_ptr; set row_ptr[N]
__global__ __launch_bounds__(256) void scan_finalize(int* __restrict__ row_ptr,
                                                     const int* __restrict__ bsums,
                                                     int n, int nnzT) {
    __shared__ int wsum[4];
    const int t = threadIdx.x, lane = t & 63, w = t >> 6;
    int s = 0;
    for (int i = t; i < (int)blockIdx.x; i += 256) s += bsums[i];
#pragma unroll
    for (int d = 1; d < 64; d <<= 1) s += __shfl_xor(s, d);
    if (lane == 0) wsum[w] = s;
    __syncthreads();
    const int off = wsum[0] + wsum[1] + wsum[2] + wsum[3];
    const int base = blockIdx.x * SCAN_CHUNK + t * 8;
#pragma unroll
    for (int j = 0; j < 8; ++j) {
        const int i = base + j;
        if (i < n) row_ptr[i] += off;
    }
    if (blockIdx.x == 0 && t == 0) row_ptr[n] = nnzT;
}

// atomic-free scatter: pos = row_ptr[dest] + rank[e]
__global__ __launch_bounds__(256) void scatter_both(
    const int* __restrict__ r1, const int* __restrict__ c1, const float* __restrict__ v1, int nnz1,
    const int* __restrict__ r2, const int* __restrict__ c2, const float* __restrict__ v2, int nnz2,
    int n1, const int* __restrict__ row_ptr, const int* __restrict__ rank,
    unsigned long long* __restrict__ csr)
{
    const int gtid = blockIdx.x * 256 + threadIdx.x;
    const int gstride = gridDim.x * 256;
    for (int e = gtid; e < nnz1; e += gstride) {
        int p = row_ptr[c1[e]] + rank[e];
        csr[p] = ((unsigned long long)__float_as_uint(__builtin_nontemporal_load(&v1[e])) << 32)
                 | (unsigned)__builtin_nontemporal_load(&r1[e]);
    }
    for (int e = gtid; e < nnz2; e += gstride) {
        int p = row_ptr[n1 + c2[e]] + rank[nnz1 + e];
        csr[p] = ((unsigned long long)__float_as_uint(__builtin_nontemporal_load(&v2[e])) << 32)
                 | (unsigned)__builtin_nontemporal_load(&r2[e]);
    }
}

// ---------------- dense GEMM: h = bf16(x @ W), both inputs in one launch ----------------
__global__ __launch_bounds__(256) void gemm_all(
    const float* __restrict__ x0, const float* __restrict__ W1, short* __restrict__ h0, int t0,
    const float* __restrict__ x1, const float* __restrict__ W2, short* __restrict__ h1, int t1,
    int g0)
{
    const float* __restrict__ x; const float* __restrict__ W; short* __restrict__ h;
    int ntiles, bidx, nblk;
    if ((int)blockIdx.x < g0) { x = x0; W = W1; h = h0; ntiles = t0; bidx = blockIdx.x;       nblk = g0; }
    else                      { x = x1; W = W2; h = h1; ntiles = t1; bidx = blockIdx.x - g0; nblk = gridDim.x - g0; }

    __shared__ short Bfrag[4][8][64][8];   // [kk][nb][lane][j] = 32 KB, lane-linear 16B slots
    for (int slot = threadIdx.x; slot < 2048; slot += 256) {
        const int lane = slot & 63, nb = (slot >> 6) & 7, kk = slot >> 9;
        const int n  = nb * 16 + (lane & 15);
        const int k0 = kk * 32 + (lane >> 4) * 8;
        union { bf16x8 v; short s[8]; } f;
#pragma unroll
        for (int j = 0; j < 8; ++j) f.s[j] = f2bf(W[(k0 + j) * CDIM + n]);
        *(bf16x8*)&Bfrag[kk][nb][lane][0] = f.v;
    }
    __syncthreads();

    const int lane = threadIdx.x & 63;
    const int wid  = threadIdx.x >> 6;
    const int l15  = lane & 15;
    const int l4   = lane >> 4;

    for (int tile = bidx * 4 + wid; tile < ntiles; tile += nblk * 4) {
        const int rbase = tile << 4;
        const int row = rbase + l15;
        const float* __restrict__ xr = x + (long)row * CDIM + (l4 << 3);

        union { bf16x8 v; short s[8]; } X[4];
#pragma unroll
        for (int kk = 0; kk < 4; ++kk) {
            f32x4 a0 = __builtin_nontemporal_load((const f32x4*)(xr + kk * 32));
            f32x4 a1 = __builtin_nontemporal_load((const f32x4*)(xr + kk * 32 + 4));
#pragma unroll
            for (int j = 0; j < 4; ++j) { X[kk].s[j] = f2bf(a0[j]); X[kk].s[4 + j] = f2bf(a1[j]); }
        }

        f32x4 c[8];
#pragma unroll
        for (int nb = 0; nb < 8; ++nb) c[nb] = (f32x4){0.f, 0.f, 0.f, 0.f};
#pragma unroll
        for (int kk = 0; kk < 4; ++kk)
#pragma unroll
            for (int nb = 0; nb < 8; ++nb)
                c[nb] = __builtin_amdgcn_mfma_f32_16x16x32_bf16(
                            *(const bf16x8*)&Bfrag[kk][nb][lane][0], X[kk].v, c[nb], 0, 0, 0);

        short* __restrict__ hr = h + (long)row * CDIM + (l4 << 2);
#pragma unroll
        for (int nb = 0; nb < 8; ++nb) {
            bf16x4 p;
#pragma unroll
            for (int ri = 0; ri < 4; ++ri) p[ri] = f2bf(c[nb][ri]);
            *(bf16x4*)(hr + (nb << 4)) = p;
        }
    }
}

// ---------------- gather-aggregate-sigmoid ----------------
// 16 lanes per dest row. Lane t16 fetches csr[beg+t16] (one load covers <=16
// edges). Batch-of-8: issue up to 8 h-row gathers back-to-back (all in flight
// concurrently), THEN fma -> ~1 latency exposure per wave for deg<=8 (99.9%).
__global__ __launch_bounds__(256) void agg_all(
    const short* __restrict__ h0, const short* __restrict__ h1,
    const int* __restrict__ row_ptr, const unsigned long long* __restrict__ csr,
    float* __restrict__ out, int n1, int nnzT)
{
    const int lane = threadIdx.x & 63;
    const int wid  = threadIdx.x >> 6;
    const int g    = lane >> 4;
    const int t16  = lane & 15;
    const int r = blockIdx.x * 16 + wid * 4 + g;
    const short* __restrict__ h = (r < n1) ? h0 : h1;   // n1 % 16 == 0 -> block-uniform
    const int beg = row_ptr[r];
    const int end = row_ptr[r + 1];
    const int deg = end - beg;

    int fi = beg + t16; if (fi > nnzT - 1) fi = nnzT - 1;
    const unsigned long long my = __builtin_nontemporal_load(&csr[fi]);

    const int m = deg < 16 ? deg : 16;
    const int gbase = g << 4;
    float acc[8] = {0.f, 0.f, 0.f, 0.f, 0.f, 0.f, 0.f, 0.f};

    bf16x8 hv[8]; float vv[8];
    // ---- batch 1: edges 0..7, loads issued back-to-back before any use ----
#pragma unroll
    for (int j = 0; j < 8; ++j) {
        if (j < m) {
            unsigned long long pv = __shfl(my, gbase + j);
            vv[j] = __uint_as_float((unsigned)(pv >> 32));
            hv[j] = *(const bf16x8*)(h + (long)(unsigned)(pv & 0xffffffffu) * CDIM + (t16 << 3));
        }
    }
#pragma unroll
    for (int j = 0; j < 8; ++j) {
        if (j < m) {
            union { bf16x8 v; unsigned u[4]; } H; H.v = hv[j];
#pragma unroll
            for (int d = 0; d < 4; ++d) {
                acc[2 * d]     += vv[j] * __uint_as_float(H.u[d] << 16);
                acc[2 * d + 1] += vv[j] * __uint_as_float(H.u[d] & 0xffff0000u);
            }
        }
    }
    // ---- batch 2: edges 8..15 (rare) ----
    if (__any(m > 8)) {
#pragma unroll
        for (int j = 8; j < 16; ++j) {
            if (j < m) {
                unsigned long long pv = __shfl(my, gbase + j);
                vv[j - 8] = __uint_as_float((unsigned)(pv >> 32));
                hv[j - 8] = *(const bf16x8*)(h + (long)(unsigned)(pv & 0xffffffffu) * CDIM + (t16 << 3));
            }
        }
#pragma unroll
        for (int j = 8; j < 16; ++j) {
            if (j < m) {
                union { bf16x8 v; unsigned u[4]; } H; H.v = hv[j - 8];
#pragma unroll
                for (int d = 0; d < 4; ++d) {
                    acc[2 * d]     += vv[j - 8] * __uint_as_float(H.u[d] << 16);
                    acc[2 * d + 1] += vv[j - 8] * __uint_as_float(H.u[d] & 0xffff0000u);
                }
            }
        }
    }
    // ---- serial tail for deg > 16 (statistically ~never) ----
    for (int i = beg + 16; i < end; ++i) {
        const unsigned long long pv = csr[i];
        const float val = __uint_as_float((unsigned)(pv >> 32));
        union { bf16x8 v; unsigned u[4]; } H;
        H.v = *(const bf16x8*)(h + (long)(unsigned)(pv & 0xffffffffu) * CDIM + (t16 << 3));
#pragma unroll
        for (int d = 0; d < 4; ++d) {
            acc[2 * d]     += val * __uint_as_float(H.u[d] << 16);
            acc[2 * d + 1] += val * __uint_as_float(H.u[d] & 0xffff0000u);
        }
    }

    f32x4 o0, o1;
#pragma unroll
    for (int j = 0; j < 4; ++j) {
        o0[j] = 1.0f / (1.0f + __expf(-acc[j]));
        o1[j] = 1.0f / (1.0f + __expf(-acc[4 + j]));
    }
    float* __restrict__ orow = out + (long)r * CDIM + (t16 << 3);
    __builtin_nontemporal_store(o0, (f32x4*)orow);
    __builtin_nontemporal_store(o1, (f32x4*)(orow + 4));
}

// ---------------- launch ----------------

extern "C" void kernel_launch(void* const* d_in, const int* in_sizes, int n_in,
                              void* d_out, int out_size, void* d_ws, size_t ws_size,
                              hipStream_t stream) {
    const float* x0 = (const float*)d_in[0];
    const float* x1 = (const float*)d_in[1];
    const float* W1 = (const float*)d_in[3];
    const float* W2 = (const float*)d_in[4];
    const int*   b1r = (const int*)d_in[5];
    const int*   b1c = (const int*)d_in[6];
    const float* b1v = (const float*)d_in[7];
    const int*   b2r = (const int*)d_in[8];
    const int*   b2c = (const int*)d_in[9];
    const float* b2v = (const float*)d_in[10];
    const int nnz1 = in_sizes[5];
    const int nnz2 = in_sizes[8];
    const int n0 = in_sizes[0] / CDIM;   // 100000
    const int n1 = in_sizes[1] / CDIM;   // 400000 (x1 rows = out1 rows)
    const int n2 = in_sizes[2] / CDIM;   // 300000
    const int N  = n1 + n2;              // combined dest space
    const int nnzT = nnz1 + nnz2;

    // workspace carve-up (ints unless noted)
    int* counts  = (int*)d_ws;                 // N
    int* row_ptr = counts + N;                 // N+1
    int* rank    = row_ptr + N + 1;            // nnzT
    int* bsums   = rank + nnzT;                // 512
    size_t iofs = (size_t)2 * N + 1 + nnzT + 512;
    iofs = (iofs + 1) & ~(size_t)1;            // 8B align
    unsigned long long* csr = (unsigned long long*)((int*)d_ws + iofs);  // nnzT (8B each)
    short* h0 = (short*)(csr + nnzT);          // n0*128 bf16
    short* h1 = h0 + (size_t)n0 * CDIM;        // n1*128 bf16

    float* out = (float*)d_out;                // rows [0, N) x 128

    const int nchunks = (N + SCAN_CHUNK - 1) / SCAN_CHUNK;  // 342 <= 512

    zero_ints<<<1024, 256, 0, stream>>>(counts, N);
    hist_rank<<<2048, 256, 0, stream>>>(b1c, nnz1, b2c, nnz2, n1, counts, rank);
    scan_chunks<<<nchunks, 256, 0, stream>>>(counts, row_ptr, bsums, N);
    scan_finalize<<<nchunks, 256, 0, stream>>>(row_ptr, bsums, N, nnzT);
    scatter_both<<<2048, 256, 0, stream>>>(b1r, b1c, b1v, nnz1, b2r, b2c, b2v, nnz2,
                                           n1, row_ptr, rank, csr);

    const int t0 = n0 >> 4, t1 = n1 >> 4;
    gemm_all<<<2048, 256, 0, stream>>>(x0, W1, h0, t0, x1, W2, h1, t1, 416);

    agg_all<<<N >> 4, 256, 0, stream>>>(h0, h1, row_ptr, csr, out, n1, nnzT);
}